// Round 1
// baseline (273.817 us; speedup 1.0000x reference)
//
#include <hip/hip_runtime.h>
#include <stdint.h>

#define D      2048
#define NE     64
#define TOPK   8
#define BM     64
#define BK     64
#define CHUNKS (D / BK)          // 32
#define NTOK   16384
#define PROBS_OFF 0
#define IDX_OFF   131072
#define BIAS_OFF  262144
#define EMA_OFF   262208

__device__ __forceinline__ void gload_lds16(const void* g, void* l) {
  __builtin_amdgcn_global_load_lds(
      (const __attribute__((address_space(1))) void*)g,
      (__attribute__((address_space(3))) void*)l,
      16, 0, 0);
}

__global__ __launch_bounds__(256) void router_main(
    const float* __restrict__ x, const float* __restrict__ gw,
    const float* __restrict__ bias, float* __restrict__ out,
    unsigned* __restrict__ gcnt) {

  __shared__ float xs[2][BM * BK];   // swizzled, 16 KB each
  __shared__ float ws[2][NE * BK];   // swizzled, 16 KB each
  __shared__ float llds[BM * 65];    // logits, pad-65 rows
  __shared__ unsigned cntL[NE];

  const int tid  = threadIdx.x;
  const int blk  = blockIdx.x;
  const int wave = tid >> 6;
  const int lane = tid & 63;
  const int tx   = tid & 15;   // token group (4 tokens)
  const int ty   = tid >> 4;   // expert group (4 experts)

  if (tid < NE) cntL[tid] = 0;

  // per-thread fragment byte offsets (sector-swizzled)
  int aX[4], aW[4];
#pragma unroll
  for (int i = 0; i < 4; ++i) {
    int mm = tx * 4 + i;
    aX[i] = mm * 256 + ((mm >> 2) & 15) * 16;
    int ee = ty * 4 + i;
    aW[i] = ee * 256 + ((ee >> 2) & 15) * 16;
  }

  const float* xsrc = x + (size_t)blk * BM * D;
  const int l16 = lane >> 4;      // sub-row within issue
  const int sct = lane & 15;      // sector

  // stage one BK chunk into buffer b: 16 issues of 1 KB for each of xs/ws,
  // 4 issues per wave. Global source is pre-swizzled so linear LDS dest
  // yields the XOR-sector-swizzled layout (rule #21).
  auto stage = [&](int b, int k0) {
#pragma unroll
    for (int ii = 0; ii < 4; ++ii) {
      int q = wave * 4 + ii;               // issue id 0..15
      int row = q * 4 + l16;               // tile row
      int kk  = k0 + ((sct ^ q) & 15) * 4; // swizzled k offset
      gload_lds16(xsrc + (size_t)row * D + kk, &xs[b][q * 256]);
      gload_lds16(gw   + (size_t)row * D + kk, &ws[b][q * 256]);
    }
  };

  float acc[4][4];
#pragma unroll
  for (int i = 0; i < 4; ++i)
#pragma unroll
    for (int j = 0; j < 4; ++j) acc[i][j] = 0.0f;

  stage(0, 0);

  for (int c = 0; c < CHUNKS; ++c) {
    __syncthreads();
    if (c + 1 < CHUNKS) stage((c + 1) & 1, (c + 1) * BK);
    const char* xb = (const char*)xs[c & 1];
    const char* wb = (const char*)ws[c & 1];
#pragma unroll
    for (int k4 = 0; k4 < 16; ++k4) {
      float4 xv[4], wv[4];
#pragma unroll
      for (int i = 0; i < 4; ++i)
        xv[i] = *(const float4*)(xb + (aX[i] ^ (k4 << 4)));
#pragma unroll
      for (int j = 0; j < 4; ++j)
        wv[j] = *(const float4*)(wb + (aW[j] ^ (k4 << 4)));
#pragma unroll
      for (int i = 0; i < 4; ++i)
#pragma unroll
        for (int j = 0; j < 4; ++j) {
          acc[i][j] = fmaf(xv[i].x, wv[j].x, acc[i][j]);
          acc[i][j] = fmaf(xv[i].y, wv[j].y, acc[i][j]);
          acc[i][j] = fmaf(xv[i].z, wv[j].z, acc[i][j]);
          acc[i][j] = fmaf(xv[i].w, wv[j].w, acc[i][j]);
        }
    }
  }

  // epilogue: logits (+bias) -> LDS
  float bj[4];
#pragma unroll
  for (int j = 0; j < 4; ++j) bj[j] = bias[ty * 4 + j];
#pragma unroll
  for (int i = 0; i < 4; ++i)
#pragma unroll
    for (int j = 0; j < 4; ++j)
      llds[(tx * 4 + i) * 65 + (ty * 4 + j)] = acc[i][j] + bj[j];
  __syncthreads();

  if (tid < BM) {
    // lane = token; exact serial top-8 (stable: lowest index wins ties)
    float v[NE];
#pragma unroll
    for (int e = 0; e < NE; ++e) v[e] = llds[tid * 65 + e];

    unsigned long long used = 0;
    float bv[TOPK];
    int   bi[TOPK];
#pragma unroll
    for (int p = 0; p < TOPK; ++p) {
      float m = -__builtin_inff();
      int mi = 0;
#pragma unroll
      for (int e = 0; e < NE; ++e) {
        bool ok = (((used >> e) & 1ull) == 0ull) && (v[e] > m);
        m  = ok ? v[e] : m;
        mi = ok ? e : mi;
      }
      used |= (1ull << mi);
      bv[p] = m;
      bi[p] = mi;
    }

    float pex[TOPK];
    float s = 0.0f;
#pragma unroll
    for (int p = 0; p < TOPK; ++p) { pex[p] = expf(bv[p] - bv[0]); s += pex[p]; }
    float inv = 1.0f / s;

    int tok = blk * BM + tid;
    float4 o0 = make_float4(pex[0] * inv, pex[1] * inv, pex[2] * inv, pex[3] * inv);
    float4 o1 = make_float4(pex[4] * inv, pex[5] * inv, pex[6] * inv, pex[7] * inv);
    *(float4*)(out + PROBS_OFF + (size_t)tok * 8)     = o0;
    *(float4*)(out + PROBS_OFF + (size_t)tok * 8 + 4) = o1;
    float4 i0 = make_float4((float)bi[0], (float)bi[1], (float)bi[2], (float)bi[3]);
    float4 i1 = make_float4((float)bi[4], (float)bi[5], (float)bi[6], (float)bi[7]);
    *(float4*)(out + IDX_OFF + (size_t)tok * 8)     = i0;
    *(float4*)(out + IDX_OFF + (size_t)tok * 8 + 4) = i1;

#pragma unroll
    for (int p = 0; p < TOPK; ++p) atomicAdd(&cntL[bi[p]], 1u);
  }
  __syncthreads();
  if (tid < NE) atomicAdd(&gcnt[tid], cntL[tid]);
}

__global__ __launch_bounds__(64) void router_finalize(
    const unsigned* __restrict__ gcnt, const float* __restrict__ bias,
    const float* __restrict__ ema, float* __restrict__ out) {
  int e = threadIdx.x;
  float load = (float)gcnt[e] * (1.0f / (float)NTOK);
  float ne = ema[e] * 0.95f + load * 0.05f;
  float nb = bias[e] + 0.01f * (1.0f / 64.0f - ne);
  out[BIAS_OFF + e] = nb;
  out[EMA_OFF + e]  = ne;
}

extern "C" void kernel_launch(void* const* d_in, const int* in_sizes, int n_in,
                              void* d_out, int out_size, void* d_ws, size_t ws_size,
                              hipStream_t stream) {
  const float* x    = (const float*)d_in[0];
  const float* gw   = (const float*)d_in[1];
  const float* bias = (const float*)d_in[2];
  const float* ema  = (const float*)d_in[3];
  float* out = (float*)d_out;
  unsigned* gcnt = (unsigned*)d_ws;

  hipMemsetAsync(d_ws, 0, NE * sizeof(unsigned), stream);
  router_main<<<dim3(NTOK / BM), dim3(256), 0, stream>>>(x, gw, bias, out, gcnt);
  router_finalize<<<dim3(1), dim3(64), 0, stream>>>(gcnt, bias, ema, out);
}